// Round 1
// 898.377 us; speedup vs baseline: 1.0205x; 1.0205x over previous
//
#include <hip/hip_runtime.h>
#include <hip/hip_bf16.h>
#include <math.h>

// ---------------------------------------------------------------------------
// DFNPureModel round 4:
//   Pre-selection GEMMs: bf16x3 emulation recast as ONE plain bf16 GEMM over
//   virtual K' = 3*512 = 1536 via a per-K-tile segment pointer table:
//     seg0: Ahi*Bhi, seg1: Ahi*Blo, seg2: Alo*Bhi  (== hi*hi + hi*lo + lo*hi)
//   Loop restructured to double-buffered LDS (stage next || compute cur),
//   ONE barrier per K-step (was 2 + full drain before compute).
//   XCD-aware block swizzle for A-panel L2 reuse.
//   coords fused into df epilogue; squared importance fused into ef epilogue
//   (atomicAdd + shfl reduce); sqrt moved into top-k. Removes 2 dispatches
//   and ~200 MB of traffic.
//   Post-selection GEMMs get the same dbuf loop. Attn unchanged.
// ---------------------------------------------------------------------------

typedef __attribute__((ext_vector_type(8))) short bf16x8;
typedef __attribute__((ext_vector_type(4))) float f32x4;

__device__ __forceinline__ float gelu_exact(float x) {
    return 0.5f * x * (1.0f + erff(x * 0.7071067811865476f));
}

__device__ __forceinline__ void async_copy16(const void* g, void* l) {
    __builtin_amdgcn_global_load_lds(
        (const __attribute__((address_space(1))) unsigned int*)g,
        (__attribute__((address_space(3))) unsigned int*)l, 16, 0, 0);
}

// ===================== elementwise fp32 -> (hi, lo) bf16 split ==============
__global__ __launch_bounds__(256) void split_kernel(
    const float* __restrict__ in,
    __hip_bfloat16* __restrict__ hi, __hip_bfloat16* __restrict__ lo)
{
    const int i4 = blockIdx.x * 256 + threadIdx.x;
    const float4 v = ((const float4*)in)[i4];
    __hip_bfloat16 h0 = __float2bfloat16(v.x);
    __hip_bfloat16 h1 = __float2bfloat16(v.y);
    __hip_bfloat16 h2 = __float2bfloat16(v.z);
    __hip_bfloat16 h3 = __float2bfloat16(v.w);
    __hip_bfloat16 l0 = __float2bfloat16(v.x - __bfloat162float(h0));
    __hip_bfloat16 l1 = __float2bfloat16(v.y - __bfloat162float(h1));
    __hip_bfloat16 l2 = __float2bfloat16(v.z - __bfloat162float(h2));
    __hip_bfloat16 l3 = __float2bfloat16(v.w - __bfloat162float(h3));
    union { __hip_bfloat16 h[4]; short4 s; } uh, ul;
    uh.h[0] = h0; uh.h[1] = h1; uh.h[2] = h2; uh.h[3] = h3;
    ul.h[0] = l0; ul.h[1] = l1; ul.h[2] = l2; ul.h[3] = l3;
    ((short4*)hi)[i4] = uh.s;
    ((short4*)lo)[i4] = ul.s;
}

// ============ W [K][N] fp32 -> WT hi/lo [Npad][K] bf16 (zero-padded) ========
__global__ __launch_bounds__(256) void transpose_split_kernel(
    const float* __restrict__ in,
    __hip_bfloat16* __restrict__ outH, __hip_bfloat16* __restrict__ outL,
    int K, int N)
{
    __shared__ float tile[32][33];
    const int k0 = blockIdx.y * 32, n0 = blockIdx.x * 32;
    const int t = threadIdx.x;
    const int lr = t >> 5, lc = t & 31;
    #pragma unroll
    for (int p = 0; p < 4; p++) {
        const int r = p * 8 + lr;
        const int n = n0 + lc;
        tile[r][lc] = (n < N) ? in[(size_t)(k0 + r) * N + n] : 0.f;
    }
    __syncthreads();
    #pragma unroll
    for (int p = 0; p < 4; p++) {
        const int r = p * 8 + lr;
        const float v = tile[lc][r];
        const __hip_bfloat16 h = __float2bfloat16(v);
        const __hip_bfloat16 l = __float2bfloat16(v - __bfloat162float(h));
        outH[(size_t)(n0 + r) * K + k0 + lc] = h;
        outL[(size_t)(n0 + r) * K + k0 + lc] = l;
    }
}

// ================= init: IMP = 0, CRD = bc (atomic accumulators) ============
__global__ __launch_bounds__(256) void init_kernel(
    float* __restrict__ IMP, float* __restrict__ CRD,
    const float* __restrict__ bc)
{
    const int t = blockIdx.x * 256 + threadIdx.x;   // 0..32767
    IMP[t] = 0.f;
    ((float2*)CRD)[t] = make_float2(bc[0], bc[1]);
}

// ===================== K-concat bf16 GEMM (pre-selection) ===================
// Virtual K' = 1536 over segments {Ahi*Bhi, Ahi*Blo, Alo*Bhi}.
// 128x128 tile, BK=32, 4 waves 2x2, double-buffered LDS, 1 barrier/K-step.
// FUSE: 0 = none, 1 = coords (df@Wc -> atomicAdd FO[row*2..]),
//       2 = squared importance (-> atomicAdd FO[row]).
template<bool GELU, bool RANK2, bool SPLIT, bool BOUNDS, int FUSE>
__global__ __launch_bounds__(256, 4) void gemm3k(
    const __hip_bfloat16* __restrict__ Ahi, const __hip_bfloat16* __restrict__ Alo,
    const __hip_bfloat16* __restrict__ Bhi, const __hip_bfloat16* __restrict__ Blo,
    const float* __restrict__ bias,
    float* __restrict__ Cf, int ldc,
    __hip_bfloat16* __restrict__ Chi, __hip_bfloat16* __restrict__ Clo,
    int N,
    const float* __restrict__ A2, const float* __restrict__ W2r,
    float* __restrict__ FO, const float* __restrict__ Wc)
{
    constexpr int K = 512;          // physical K of every pre-selection GEMM
    constexpr int NPS = K / 32;     // K-steps per segment (16)
    constexpr int NSTEPS = 3 * NPS; // 48
    __shared__ __align__(16) __hip_bfloat16 As[2][128][32];
    __shared__ __align__(16) __hip_bfloat16 Bs[2][128][32];
    const int t = threadIdx.x;
    const int wave = t >> 6, lane = t & 63;
    const int wave_m = wave >> 1, wave_n = wave & 1;
    const int fr = lane & 15, quad = lane >> 4;
    // XCD-aware bijective swizzle of the linear block id (nwg % 8 == 0)
    const int gx = gridDim.x;
    const int nwg = gx * gridDim.y;
    int lid = blockIdx.y * gx + blockIdx.x;
    if ((nwg & 7) == 0) {
        const int chunk = nwg >> 3;
        lid = (lid & 7) * chunk + (lid >> 3);
    }
    const int m0 = (lid / gx) * 128;
    const int n0 = (lid % gx) * 128;
    const int srow = lane >> 2;       // 0..15
    const int skc  = (lane & 3) * 8;  // element offset within 32-col row

    f32x4 acc[4][4] = {};

    auto STAGE = [&](int buf, int step) {
        int seg = 0, ts = step;
        if (ts >= NPS) { ts -= NPS; seg = 1; }
        if (ts >= NPS) { ts -= NPS; seg = 2; }
        const int kk = ts << 5;
        const __hip_bfloat16* Ab = (seg == 2) ? Alo : Ahi;
        const __hip_bfloat16* Bb = (seg == 1) ? Blo : Bhi;
        #pragma unroll
        for (int s = 0; s < 2; s++) {
            const int r = wave * 32 + s * 16 + srow;
            async_copy16(Ab + (size_t)(m0 + r) * K + kk + skc,
                         &As[buf][wave * 32 + s * 16][0]);
            async_copy16(Bb + (size_t)(n0 + r) * K + kk + skc,
                         &Bs[buf][wave * 32 + s * 16][0]);
        }
    };

    STAGE(0, 0);
    __syncthreads();                  // drains vmcnt(0)
    int cur = 0;
    for (int step = 0; step < NSTEPS; ++step) {
        if (step + 1 < NSTEPS) STAGE(cur ^ 1, step + 1);  // loads fly over MFMA
        bf16x8 af[4], bfv[4];
        #pragma unroll
        for (int i = 0; i < 4; i++)
            af[i] = *(const bf16x8*)&As[cur][wave_m * 64 + i * 16 + fr][quad * 8];
        #pragma unroll
        for (int j = 0; j < 4; j++)
            bfv[j] = *(const bf16x8*)&Bs[cur][wave_n * 64 + j * 16 + fr][quad * 8];
        #pragma unroll
        for (int i = 0; i < 4; i++)
            #pragma unroll
            for (int j = 0; j < 4; j++)
                acc[i][j] = __builtin_amdgcn_mfma_f32_16x16x32_bf16(
                    af[i], bfv[j], acc[i][j], 0, 0, 0);
        __syncthreads();              // next buffer ready + all reads of cur done
        cur ^= 1;
    }

    // epilogue: row = m0 + wave_m*64 + i*16 + quad*4 + r,
    //           col = n0 + wave_n*64 + j*16 + fr
    #pragma unroll
    for (int i = 0; i < 4; i++) {
        const int gmb = m0 + wave_m * 64 + i * 16 + quad * 4;
        float a2x[4], a2y[4];
        if (RANK2) {
            #pragma unroll
            for (int r = 0; r < 4; r++) {
                a2x[r] = A2[(size_t)(gmb + r) * 2];
                a2y[r] = A2[(size_t)(gmb + r) * 2 + 1];
            }
        }
        float f0[4] = {0.f, 0.f, 0.f, 0.f};
        float f1[4] = {0.f, 0.f, 0.f, 0.f};
        #pragma unroll
        for (int j = 0; j < 4; j++) {
            const int gn = n0 + wave_n * 64 + j * 16 + fr;
            const bool nok = !BOUNDS || (gn < N);
            const float bv = nok ? bias[gn] : 0.f;
            float w2a = 0.f, w2b = 0.f;
            if (RANK2) { w2a = W2r[gn]; w2b = W2r[512 + gn]; }
            float wcx = 0.f, wcy = 0.f;
            if (FUSE == 1) {
                const float2 wc = ((const float2*)Wc)[gn];
                wcx = wc.x; wcy = wc.y;
            }
            #pragma unroll
            for (int r = 0; r < 4; r++) {
                const int gm = gmb + r;
                float v = acc[i][j][r] + bv;
                if (RANK2) v += a2x[r] * w2a + a2y[r] * w2b;
                if (GELU) v = gelu_exact(v);
                if (SPLIT) {
                    const __hip_bfloat16 h = __float2bfloat16(v);
                    const __hip_bfloat16 l =
                        __float2bfloat16(v - __bfloat162float(h));
                    Chi[(size_t)gm * 512 + gn] = h;
                    Clo[(size_t)gm * 512 + gn] = l;
                } else if (nok) {
                    Cf[(size_t)gm * ldc + gn] = v;
                }
                if (FUSE == 1) { f0[r] += v * wcx; f1[r] += v * wcy; }
                if (FUSE == 2 && nok) f0[r] += v * v;
            }
        }
        if (FUSE) {
            #pragma unroll
            for (int r = 0; r < 4; r++) {
                float a = f0[r], b = f1[r];
                #pragma unroll
                for (int off = 1; off < 16; off <<= 1) {
                    a += __shfl_xor(a, off);
                    if (FUSE == 1) b += __shfl_xor(b, off);
                }
                if (fr == 0) {
                    if (FUSE == 1) {
                        atomicAdd(&FO[(size_t)(gmb + r) * 2],     a);
                        atomicAdd(&FO[(size_t)(gmb + r) * 2 + 1], b);
                    } else {
                        atomicAdd(&FO[gmb + r], a);
                    }
                }
            }
        }
    }
}

// ===================== selection ============================================
__global__ __launch_bounds__(1024) void topk_kernel(
    const float* __restrict__ IMP, int* __restrict__ IDX)
{
    __shared__ float v[4096];
    __shared__ int   ix[4096];
    const int b = blockIdx.x, t = threadIdx.x;
    for (int i = t; i < 4096; i += 1024) {
        v[i] = sqrtf(IMP[b * 4096 + i]);   // IMP holds squared norms
        ix[i] = i;
    }
    __syncthreads();
    for (int k = 2; k <= 4096; k <<= 1) {
        for (int j = k >> 1; j > 0; j >>= 1) {
            for (int q = 0; q < 4; q++) {
                const int i = t + (q << 10);
                const int l = i ^ j;
                if (l > i) {
                    const float vi = v[i], vl = v[l];
                    const int   ii = ix[i], il = ix[l];
                    const bool after = (vi < vl) || (vi == vl && ii > il);
                    const bool dirAsc = ((i & k) == 0);
                    if (dirAsc ? after : !after) {
                        v[i] = vl; v[l] = vi; ix[i] = il; ix[l] = ii;
                    }
                }
            }
            __syncthreads();
        }
    }
    if (t < 512) IDX[b * 512 + t] = ix[t];
}

__global__ __launch_bounds__(256) void gather_kernel(
    const float* __restrict__ EF, const int* __restrict__ IDX,
    float* __restrict__ POS, __hip_bfloat16* __restrict__ ST)
{
    const int bn  = blockIdx.x;
    const int b   = bn >> 9;
    const int row = IDX[bn];
    const float* src = EF + ((size_t)(b * 4096) + row) * 1027;
    const int t = threadIdx.x;
    if (t < 2) POS[(size_t)bn * 2 + t] = src[t];
    __hip_bfloat16* dst = ST + (size_t)bn * 1024;
    for (int k = t; k < 1024; k += 256) dst[k] = __float2bfloat16(src[2 + k]);
}

// ===================== weight transpose + fp32->bf16 (post-sel) =============
__global__ __launch_bounds__(256) void transpose_cvt_kernel(
    const float* __restrict__ in, __hip_bfloat16* __restrict__ out,
    int K, int N)
{
    __shared__ float tile[32][33];
    const int k0 = blockIdx.y * 32, n0 = blockIdx.x * 32;
    const int t = threadIdx.x;
    const int lr = t >> 5, lc = t & 31;
    #pragma unroll
    for (int p = 0; p < 4; p++) {
        const int r = p * 8 + lr;
        tile[r][lc] = in[(size_t)(k0 + r) * N + n0 + lc];
    }
    __syncthreads();
    #pragma unroll
    for (int p = 0; p < 4; p++) {
        const int r = p * 8 + lr;
        out[(size_t)(n0 + r) * K + k0 + lc] = __float2bfloat16(tile[lc][r]);
    }
}

__global__ __launch_bounds__(256) void transpose_proj_kernel(
    const __hip_bfloat16* __restrict__ in, __hip_bfloat16* __restrict__ out)
{
    __shared__ __hip_bfloat16 tile[32][33];
    const int b = blockIdx.z;
    const int n0 = blockIdx.y * 32, d0 = blockIdx.x * 32;
    const int t = threadIdx.x;
    const int lr = t >> 5, lc = t & 31;
    #pragma unroll
    for (int p = 0; p < 4; p++) {
        const int r = p * 8 + lr;
        tile[r][lc] = in[((size_t)b * 512 + n0 + r) * 512 + d0 + lc];
    }
    __syncthreads();
    #pragma unroll
    for (int p = 0; p < 4; p++) {
        const int r = p * 8 + lr;
        out[((size_t)b * 512 + d0 + r) * 512 + n0 + lc] = tile[lc][r];
    }
}

// ===================== bf16 MFMA GEMM (post-selection, dbuf) ================
template<bool GELU>
__global__ __launch_bounds__(256, 4) void gemm_post(
    const __hip_bfloat16* __restrict__ A,
    const __hip_bfloat16* __restrict__ BT,
    const float* __restrict__ bias,
    __hip_bfloat16* __restrict__ C,
    int N, int K)
{
    __shared__ __align__(16) __hip_bfloat16 As[2][128][32];
    __shared__ __align__(16) __hip_bfloat16 Bs[2][128][32];
    const int t = threadIdx.x;
    const int wave = t >> 6, lane = t & 63;
    const int wave_m = wave >> 1, wave_n = wave & 1;
    const int fr = lane & 15, quad = lane >> 4;
    const int gx = gridDim.x;
    const int nwg = gx * gridDim.y;
    int lid = blockIdx.y * gx + blockIdx.x;
    if ((nwg & 7) == 0) {
        const int chunk = nwg >> 3;
        lid = (lid & 7) * chunk + (lid >> 3);
    }
    const int m0 = (lid / gx) * 128;
    const int n0 = (lid % gx) * 128;
    const int srow = lane >> 2;
    const int skc  = (lane & 3) * 8;
    const int nsteps = K >> 5;

    f32x4 acc[4][4] = {};

    auto STAGE = [&](int buf, int step) {
        const int kk = step << 5;
        #pragma unroll
        for (int s = 0; s < 2; s++) {
            const int r = wave * 32 + s * 16 + srow;
            async_copy16(A  + (size_t)(m0 + r) * K + kk + skc,
                         &As[buf][wave * 32 + s * 16][0]);
            async_copy16(BT + (size_t)(n0 + r) * K + kk + skc,
                         &Bs[buf][wave * 32 + s * 16][0]);
        }
    };

    STAGE(0, 0);
    __syncthreads();
    int cur = 0;
    for (int step = 0; step < nsteps; ++step) {
        if (step + 1 < nsteps) STAGE(cur ^ 1, step + 1);
        bf16x8 af[4], bfv[4];
        #pragma unroll
        for (int i = 0; i < 4; i++)
            af[i] = *(const bf16x8*)&As[cur][wave_m * 64 + i * 16 + fr][quad * 8];
        #pragma unroll
        for (int j = 0; j < 4; j++)
            bfv[j] = *(const bf16x8*)&Bs[cur][wave_n * 64 + j * 16 + fr][quad * 8];
        #pragma unroll
        for (int i = 0; i < 4; i++)
            #pragma unroll
            for (int j = 0; j < 4; j++)
                acc[i][j] = __builtin_amdgcn_mfma_f32_16x16x32_bf16(
                    af[i], bfv[j], acc[i][j], 0, 0, 0);
        __syncthreads();
        cur ^= 1;
    }
    #pragma unroll
    for (int i = 0; i < 4; i++) {
        const int gm = m0 + wave_m * 64 + i * 16 + quad * 4;
        #pragma unroll
        for (int j = 0; j < 4; j++) {
            const int gn = n0 + wave_n * 64 + j * 16 + fr;
            const float bv = bias[gn];
            #pragma unroll
            for (int r = 0; r < 4; r++) {
                float v = acc[i][j][r] + bv;
                if (GELU) v = gelu_exact(v);
                C[(size_t)(gm + r) * N + gn] = __float2bfloat16(v);
            }
        }
    }
}

// ===================== fused attention output (bf16 MFMA) ===================
__global__ __launch_bounds__(256) void attn_mfma_kernel(
    const float* __restrict__ POS,
    const __hip_bfloat16* __restrict__ PROJT,
    float* __restrict__ OUT)
{
    __shared__ __align__(16) __hip_bfloat16 Bs[256][32];
    __shared__ float2 pos_s[512];
    __shared__ float srow_s[4][16];
    const int t = threadIdx.x;
    const int wave = t >> 6, lane = t & 63;
    const int fr = lane & 15, quad = lane >> 4;
    const int b  = blockIdx.z;
    const int g0 = blockIdx.x * 64;
    const int d0 = blockIdx.y * 256;

    {
        const float2* p = (const float2*)(POS + (size_t)b * 512 * 2);
        pos_s[t]       = p[t];
        pos_s[256 + t] = p[256 + t];
    }
    const int g = g0 + wave * 16 + fr;
    const bool gv = g < 10000;
    const float step = 2.0f / 99.0f;
    const int gi = gv ? (g / 100) : 0;
    const int gj = gv ? (g - gi * 100) : 0;
    const float gx = -1.f + step * (float)gi;
    const float gy = -1.f + step * (float)gj;

    f32x4 acc[16] = {};
    float wsum = 0.f;
    __syncthreads();

    for (int n0 = 0; n0 < 512; n0 += 32) {
        #pragma unroll
        for (int s = 0; s < 4; s++) {
            const int seg = wave * 4 + s;
            const __hip_bfloat16* gB = PROJT
                + ((size_t)b * 512 + d0 + seg * 16 + (lane >> 2)) * 512
                + n0 + (lane & 3) * 8;
            async_copy16(gB, &Bs[seg * 16][0]);
        }
        bf16x8 wf;
        float wl = 0.f;
        #pragma unroll
        for (int j = 0; j < 8; j++) {
            const int n = n0 + quad * 8 + j;
            const float2 pn = pos_s[n];
            const float dx = gx - pn.x, dy = gy - pn.y;
            const float w = gv ? __expf(-10.0f * (dx * dx + dy * dy)) : 0.f;
            const __hip_bfloat16 wb = __float2bfloat16(w);
            union { __hip_bfloat16 h; short s; } u; u.h = wb;
            wf[j] = u.s;
            wl += __bfloat162float(wb);
        }
        wsum += wl;
        __syncthreads();
        #pragma unroll
        for (int j = 0; j < 16; j++) {
            const bf16x8 bv = *(const bf16x8*)&Bs[j * 16 + fr][quad * 8];
            acc[j] = __builtin_amdgcn_mfma_f32_16x16x32_bf16(wf, bv, acc[j], 0, 0, 0);
        }
        __syncthreads();
    }
    wsum += __shfl_xor(wsum, 16);
    wsum += __shfl_xor(wsum, 32);
    if (lane < 16) srow_s[wave][lane] = wsum;
    __syncthreads();
    const int rbase = quad * 4;
    float inv[4];
    #pragma unroll
    for (int r = 0; r < 4; r++)
        inv[r] = 1.0f / (srow_s[wave][rbase + r] + 1e-8f);
    #pragma unroll
    for (int j = 0; j < 16; j++) {
        const int col = d0 + j * 16 + fr;
        #pragma unroll
        for (int r = 0; r < 4; r++) {
            const int gr = g0 + wave * 16 + rbase + r;
            if (gr < 10000)
                OUT[((size_t)b * 10000 + gr) * 512 + col] = acc[j][r] * inv[r];
        }
    }
}

// ===========================================================================
extern "C" void kernel_launch(void* const* d_in, const int* in_sizes, int n_in,
                              void* d_out, int out_size, void* d_ws, size_t ws_size,
                              hipStream_t stream)
{
    const float* x   = (const float*)d_in[0];
    const float* W1  = (const float*)d_in[1];
    const float* b1  = (const float*)d_in[2];
    const float* W2  = (const float*)d_in[3];
    const float* b2  = (const float*)d_in[4];
    const float* Wc  = (const float*)d_in[5];
    const float* bc  = (const float*)d_in[6];
    const float* We1 = (const float*)d_in[7];
    const float* be1 = (const float*)d_in[8];
    const float* We2 = (const float*)d_in[9];
    const float* be2 = (const float*)d_in[10];
    const float* Wo1 = (const float*)d_in[11];
    const float* bo1 = (const float*)d_in[12];
    const float* Wo2 = (const float*)d_in[13];
    const float* bo2 = (const float*)d_in[14];
    float* out = (float*)d_out;

    const size_t BS = 32768;
    const size_t ACT = BS * 512;             // elements per activation matrix
    // ---- workspace layout ----
    __hip_bfloat16* P0h = (__hip_bfloat16*)d_ws;        // 32 MB
    __hip_bfloat16* P0l = P0h + ACT;                    // 32 MB
    __hip_bfloat16* P1h = P0l + ACT;                    // 32 MB
    __hip_bfloat16* P1l = P1h + ACT;                    // 32 MB
    float* EF  = (float*)(P1l + ACT);                   // 32768x1027 fp32
    float* CRD = EF + BS * 1027;                        // 32768x2
    float* IMP = CRD + BS * 2;                          // 32768
    int*   IDX = (int*)(IMP + BS);                      // 4096
    float* POS = (float*)(IDX + 4096);                  // 4096x2
    __hip_bfloat16* W1Th = (__hip_bfloat16*)(POS + 4096 * 2);   // 512x512
    __hip_bfloat16* W1Tl = W1Th + 512 * 512;
    __hip_bfloat16* W2Th = W1Tl + 512 * 512;
    __hip_bfloat16* W2Tl = W2Th + 512 * 512;
    __hip_bfloat16* We1Th = W2Tl + 512 * 512;
    __hip_bfloat16* We1Tl = We1Th + 512 * 512;
    __hip_bfloat16* We2Th = We1Tl + 512 * 512;          // 1152x512
    __hip_bfloat16* We2Tl = We2Th + (size_t)1152 * 512;
    // post-selection pool aliases P0 (dead after h3 GEMM)
    __hip_bfloat16* ST    = P0h;                           // 4096x1024
    __hip_bfloat16* H4    = ST + (size_t)4096 * 1024;      // 4096x2048
    __hip_bfloat16* PROJ  = H4 + (size_t)4096 * 2048;      // 4096x512
    __hip_bfloat16* PROJT = PROJ + (size_t)4096 * 512;     // 8x512x512
    __hip_bfloat16* Wo1T  = PROJT + (size_t)4096 * 512;    // 2048x1024
    __hip_bfloat16* Wo2T  = Wo1T + (size_t)2048 * 1024;    // 512x2048

    dim3 blk(256);
    // ---- prep: split x, split+transpose pre-selection weights, init acc ----
    split_kernel<<<dim3(16384), blk, 0, stream>>>(x, P0h, P0l);
    transpose_split_kernel<<<dim3(16, 16), blk, 0, stream>>>(W1, W1Th, W1Tl, 512, 512);
    transpose_split_kernel<<<dim3(16, 16), blk, 0, stream>>>(W2, W2Th, W2Tl, 512, 512);
    transpose_split_kernel<<<dim3(16, 16), blk, 0, stream>>>(We1 + 2 * 512, We1Th, We1Tl, 512, 512);
    transpose_split_kernel<<<dim3(36, 16), blk, 0, stream>>>(We2, We2Th, We2Tl, 512, 1027);
    init_kernel<<<dim3(128), blk, 0, stream>>>(IMP, CRD, bc);
    // ---- pre-selection (K-concat bf16 MFMA, dbuf) ----
    // h1 = gelu(x@W1+b1) -> P1 pair
    gemm3k<true, false, true, false, 0><<<dim3(4, 256), blk, 0, stream>>>(
        P0h, P0l, W1Th, W1Tl, b1, nullptr, 0, P1h, P1l, 512,
        nullptr, nullptr, nullptr, nullptr);
    // df = gelu(h1@W2+b2) -> P0 pair; coords fused (atomicAdd into CRD)
    gemm3k<true, false, true, false, 1><<<dim3(4, 256), blk, 0, stream>>>(
        P1h, P1l, W2Th, W2Tl, b2, nullptr, 0, P0h, P0l, 512,
        nullptr, nullptr, CRD, Wc);
    // h3 = gelu(df@We1[2:] + coords@We1[:2] + be1) -> P1 pair
    gemm3k<true, true, true, false, 0><<<dim3(4, 256), blk, 0, stream>>>(
        P0h, P0l, We1Th, We1Tl, be1, nullptr, 0, P1h, P1l, 512,
        CRD, We1, nullptr, nullptr);
    // ef = h3@We2+be2 -> EF fp32 (N=1027, padded BT); squared importance fused
    gemm3k<false, false, false, true, 2><<<dim3(9, 256), blk, 0, stream>>>(
        P1h, P1l, We2Th, We2Tl, be2, EF, 1027, nullptr, nullptr, 1027,
        nullptr, nullptr, IMP, nullptr);
    // ---- selection ----
    topk_kernel<<<dim3(8), dim3(1024), 0, stream>>>(IMP, IDX);
    // ---- post-selection weight prep (P0 pool free from here) ----
    transpose_cvt_kernel<<<dim3(64, 32), blk, 0, stream>>>(Wo1, Wo1T, 1024, 2048);
    transpose_cvt_kernel<<<dim3(16, 64), blk, 0, stream>>>(Wo2, Wo2T, 2048, 512);
    gather_kernel<<<dim3(4096), blk, 0, stream>>>(EF, IDX, POS, ST);
    // ---- post-selection (bf16 MFMA, dbuf) ----
    gemm_post<true><<<dim3(16, 32), blk, 0, stream>>>(
        ST, Wo1T, bo1, H4, 2048, 1024);
    gemm_post<false><<<dim3(4, 32), blk, 0, stream>>>(
        H4, Wo2T, bo2, PROJ, 512, 2048);
    transpose_proj_kernel<<<dim3(16, 16, 8), blk, 0, stream>>>(PROJ, PROJT);
    attn_mfma_kernel<<<dim3(157, 2, 8), blk, 0, stream>>>(POS, PROJT, out);
}